// Round 4
// baseline (1646.732 us; speedup 1.0000x reference)
//
#include <hip/hip_runtime.h>
#include <hip/hip_bf16.h>
#include <float.h>

#define DEV __device__ __forceinline__

using f32x4 = __attribute__((ext_vector_type(4))) float;
using f4v   = __attribute__((ext_vector_type(4))) float;
using bfrag = __attribute__((ext_vector_type(8))) short;     // 8 bf16
using hfrag = __attribute__((ext_vector_type(8))) _Float16;  // 8 f16
using us8   = __attribute__((ext_vector_type(8))) unsigned short;

DEV unsigned short f2bf(float f) {
  unsigned u = __builtin_bit_cast(unsigned, f);
  u += 0x7FFFu + ((u >> 16) & 1u);
  return (unsigned short)(u >> 16);
}
DEV float bf2f(unsigned short h) {
  unsigned u = ((unsigned)h) << 16;
  return __builtin_bit_cast(float, u);
}
DEV f32x4 mfma_bf(bfrag a, bfrag b, f32x4 c) {
  return __builtin_amdgcn_mfma_f32_16x16x32_bf16(a, b, c, 0, 0, 0);
}
DEV f32x4 mfma_h(hfrag a, hfrag b, f32x4 c) {
  return __builtin_amdgcn_mfma_f32_16x16x32_f16(a, b, c, 0, 0, 0);
}

// XOR-swizzled LDS byte offset for row-major tiles of RB bytes/row (T2 pattern)
template<int RB>
DEV unsigned swz(int row, int colb) {
  return (unsigned)(row * RB) +
         (((unsigned)colb) ^ (((unsigned)(row << 4)) & (unsigned)(RB - 1)));
}
template<int RB>
DEV bfrag ldfragB(const unsigned short* base, int row, int kcol) {
  return *(const bfrag*)((const char*)base + swz<RB>(row, kcol * 2));
}
template<int RB>
DEV hfrag ldfragH(const _Float16* base, int row, int kcol) {
  return *(const hfrag*)((const char*)base + swz<RB>(row, kcol * 2));
}

// stage 64 rows of C floats -> bf16 hi/lo LDS tiles [64][C32], one 8-col chunk
// per thread (1024-thread block; threads >= 64*C32/8 idle)
template<int C, int C32>
DEV void stageHL(const float* __restrict__ src, unsigned short* H,
                 unsigned short* L, int tid) {
  constexpr int RB  = C32 * 2;
  constexpr int CH8 = C32 / 8;
  if (tid < 64 * CH8) {
    const int row = tid / CH8, cb = (tid % CH8) * 8;
    float f[8];
    if constexpr (C % 8 == 0) {
      *(f4v*)(f + 0) = *(const f4v*)(src + row * C + cb);
      *(f4v*)(f + 4) = *(const f4v*)(src + row * C + cb + 4);
    } else {
#pragma unroll
      for (int e = 0; e < 8; ++e) {
        const int c = cb + e;
        f[e] = (c < C) ? src[row * C + c] : 0.f;
      }
    }
    us8 hv, lv;
#pragma unroll
    for (int e = 0; e < 8; ++e) {
      const unsigned short hs = f2bf(f[e]);
      hv[e] = hs;
      lv[e] = f2bf(f[e] - bf2f(hs));
    }
    const unsigned off = swz<RB>(row, cb * 2);
    *(us8*)((char*)H + off) = hv;
    *(us8*)((char*)L + off) = lv;
  }
}

// value-only full-wave bitonic sort, descending across lanes
DEV void vsort64(float& v, int lane) {
#pragma unroll
  for (int k = 2; k <= 64; k <<= 1) {
#pragma unroll
    for (int j = k >> 1; j > 0; j >>= 1) {
      const float ov = __shfl_xor(v, j);
      const bool keepMax = (((lane & j) == 0) != ((lane & k) != 0));
      v = keepMax ? fmaxf(v, ov) : fminf(v, ov);
    }
  }
}

// merge running top-20 (tv, desc in lanes 0..19) with sorted-64 desc (nv)
// -> new sorted desc across lanes (top-20 in lanes 0..19)
DEV float merge20(float tv, float nv, int lane) {
  const float rev = __shfl(nv, 63 - lane);
  float x = (lane < 20) ? tv : ((lane >= 44) ? rev : -FLT_MAX);
#pragma unroll
  for (int j = 32; j > 0; j >>= 1) {
    const float ov = __shfl_xor(x, j);
    x = ((lane & j) == 0) ? fmaxf(x, ov) : fminf(x, ov);
  }
  return x;
}

// ---------------- squared norms ----------------
template<int C>
__global__ __launch_bounds__(256)
void sq_kernel(const float* __restrict__ x, float* __restrict__ sq) {
  const int i = blockIdx.x * 256 + threadIdx.x;
  const float* r = x + (size_t)i * C;
  float s = 0.f;
#pragma unroll
  for (int c = 0; c < C; c += 4) {
    f4v v = *(const f4v*)(r + c);
    s += v[0] * v[0] + v[1] * v[1] + v[2] * v[2] + v[3] * v[3];
  }
  sq[i] = s;
}

// ---------------- fused kNN: values-only top-20 sweep + index-recovery sweep --
// grid: b(8) x i-tile(32) = 256 blocks, 1024 threads (16 waves).
// MFMA: wave w computes quadrant (w>>2, w&3) of the 64x64 score tile.
// Sweep 1: per-row running top-20 VALUES via bitonic sort+merge (no indices).
// Sweep 2: recompute scores (bitwise identical), collect j with sc >= v20
// via ballot + popc prefix. Order of indices is arbitrary (max_k is
// order-invariant downstream).
template<int C, int C32>
__global__ __launch_bounds__(1024)
void knn_kernel(const float* __restrict__ x, const float* __restrict__ sqg,
                int* __restrict__ idx_out) {
  constexpr int N = 2048, TI = 64, TJ = 64, TK = 20, NT = N / TJ;
  constexpr int RB = C32 * 2;
  const int b    = blockIdx.x >> 5;
  const int i0   = (blockIdx.x & 31) * TI;
  const int tid  = threadIdx.x;
  const int lane = tid & 63;
  const int w    = tid >> 6;        // 0..15
  const int ri   = w >> 2;          // MFMA quadrant row
  const int ci   = w & 3;           // MFMA quadrant col

  __shared__ unsigned short XiH[TI * C32], XiL[TI * C32];
  __shared__ unsigned short XjH[TJ * C32], XjL[TJ * C32];
  __shared__ float S[TI][TJ + 4];
  __shared__ float sqT[2][TJ];

  const float* xb = x + (size_t)b * N * C;
  const int m15 = lane & 15;
  const int kb8 = (lane >> 4) * 8;

  stageHL<C, C32>(xb + (size_t)i0 * C, XiH, XiL, tid);

  // computes score tile jt into S (identical code both sweeps -> bitwise equal)
  auto tile_scores = [&](int jt) {
    const int j0 = jt * TJ;
    stageHL<C, C32>(xb + (size_t)j0 * C, XjH, XjL, tid);
    if (tid < TJ) sqT[jt & 1][tid] = sqg[b * N + j0 + tid];
    __syncthreads();
    f32x4 acc = {0, 0, 0, 0};
#pragma unroll
    for (int ks = 0; ks < C32 / 32; ++ks) {
      const int kc = ks * 32 + kb8;
      const bfrag ah = ldfragB<RB>(XiH, 16 * ri + m15, kc);
      const bfrag al = ldfragB<RB>(XiL, 16 * ri + m15, kc);
      const bfrag bh = ldfragB<RB>(XjH, 16 * ci + m15, kc);
      const bfrag bl = ldfragB<RB>(XjL, 16 * ci + m15, kc);
      acc = mfma_bf(ah, bh, acc);
      acc = mfma_bf(ah, bl, acc);
      acc = mfma_bf(al, bh, acc);
    }
#pragma unroll
    for (int r = 0; r < 4; ++r)
      S[16 * ri + (lane >> 4) * 4 + r][16 * ci + m15] = acc[r];
    __syncthreads();
  };

  float tv[4], t20[4];

  // ---- sweep 1: values-only top-20 ----
  for (int jt = 0; jt < NT; ++jt) {
    tile_scores(jt);
#pragma unroll
    for (int d = 0; d < 4; ++d) {
      const float sc = 2.f * S[4 * w + d][lane] - sqT[jt & 1][lane];
      if (jt == 0) {
        float v = sc;
        vsort64(v, lane);
        tv[d]  = v;
        t20[d] = __shfl(v, TK - 1);
      } else if (__ballot(sc > t20[d])) {
        float v = sc;
        vsort64(v, lane);
        tv[d]  = merge20(tv[d], v, lane);
        t20[d] = __shfl(tv[d], TK - 1);
      }
    }
  }

  // ---- sweep 2: index recovery ----
  int cnt[4] = {0, 0, 0, 0};
  const unsigned long long ltmask = (lane == 63) ? ~0ull >> 1
                                                 : (1ull << lane) - 1ull;
  for (int jt = 0; jt < NT; ++jt) {
    tile_scores(jt);
    const int j0 = jt * TJ;
#pragma unroll
    for (int d = 0; d < 4; ++d) {
      const float sc = 2.f * S[4 * w + d][lane] - sqT[jt & 1][lane];
      const unsigned long long m = __ballot(sc >= t20[d]);
      if (m) {
        const int pos = cnt[d] + __popcll(m & ltmask);
        if (((m >> lane) & 1ull) && pos < TK) {
          const int i = i0 + 4 * w + d;
          idx_out[((size_t)b * N + i) * TK + pos] = j0 + lane;
        }
        cnt[d] += __popcll(m);
      }
    }
  }
}

// ---------------- edgeconv: gather + fp16 MFMA + BN + LeakyReLU + max_k ----------------
template<int C, int C32>
__global__ __launch_bounds__(256)
void conv_kernel(const float* __restrict__ x, const int* __restrict__ idxg,
                 const float* __restrict__ W, const float* __restrict__ gam,
                 const float* __restrict__ bet, const float* __restrict__ mea,
                 const float* __restrict__ var, float* __restrict__ y) {
  constexpr int N = 2048, TK = 20, O = 64;
  constexpr int RB = C32 * 2;
  constexpr int CH8 = C32 / 8;
  const int b    = blockIdx.x >> 7;
  const int n0   = (blockIdx.x & 127) * 16;
  const int tid  = threadIdx.x;
  const int lane = tid & 63;
  const int w    = tid >> 6;

  __shared__ float    ctrF[16][C];
  __shared__ _Float16 A1[320 * C32];
  __shared__ _Float16 CtrB[16 * C32];
  __shared__ _Float16 WdT[O * C32];
  __shared__ _Float16 WcT[O * C32];

  const float* xb = x + (size_t)b * N * C;

  for (int i = tid; i < 16 * C; i += 256)
    ctrF[i / C][i % C] = xb[(size_t)(n0 + i / C) * C + (i % C)];

  for (int i = tid; i < O * CH8; i += 256) {
    const int o = i / CH8, ch = (i % CH8) * 8;
    hfrag hd, hc;
#pragma unroll
    for (int e = 0; e < 8; ++e) {
      const int c = ch + e;
      hd[e] = (c < C) ? (_Float16)W[o * 2 * C + c]     : (_Float16)0.f;
      hc[e] = (c < C) ? (_Float16)W[o * 2 * C + C + c] : (_Float16)0.f;
    }
    const unsigned off = swz<RB>(o, ch * 2);
    *(hfrag*)((char*)WdT + off) = hd;
    *(hfrag*)((char*)WcT + off) = hc;
  }
  __syncthreads();

  for (int i = tid; i < 16 * CH8; i += 256) {
    const int row = i / CH8, ch = (i % CH8) * 8;
    hfrag hv;
#pragma unroll
    for (int e = 0; e < 8; ++e) {
      const int c = ch + e;
      hv[e] = (c < C) ? (_Float16)ctrF[row][c] : (_Float16)0.f;
    }
    *(hfrag*)((char*)CtrB + swz<RB>(row, ch * 2)) = hv;
  }

  for (int r = tid; r < 16 * TK; r += 256) {
    const int n = r & 15, k = r >> 4;
    int j = idxg[((size_t)b * N + n0 + n) * TK + k];
    j &= (N - 1);  // safety clamp
    const float* xj = xb + (size_t)j * C;
#pragma unroll
    for (int ch = 0; ch < C32; ch += 8) {
      float f[8];
#pragma unroll
      for (int q = 0; q < 8; q += 4) {
        const int c = ch + q;
        if (c + 3 < C) {
          *(f4v*)(f + q) = *(const f4v*)(xj + c);
        } else {
#pragma unroll
          for (int e = 0; e < 4; ++e) f[q + e] = (c + e < C) ? xj[c + e] : 0.f;
        }
      }
      hfrag hv;
#pragma unroll
      for (int e = 0; e < 8; ++e) {
        const int c = ch + e;
        const float d = (c < C) ? (f[e] - ctrF[n][c]) : 0.f;
        hv[e] = (_Float16)d;
      }
      *(hfrag*)((char*)A1 + swz<RB>(r, ch * 2)) = hv;
    }
  }
  __syncthreads();

  const int m15 = lane & 15;
  const int kb8 = (lane >> 4) * 8;
  hfrag bd[C32 / 32], bc[C32 / 32];
#pragma unroll
  for (int ks = 0; ks < C32 / 32; ++ks) {
    bd[ks] = ldfragH<RB>(WdT, 16 * w + m15, ks * 32 + kb8);
    bc[ks] = ldfragH<RB>(WcT, 16 * w + m15, ks * 32 + kb8);
  }
  f32x4 base = {0, 0, 0, 0};
#pragma unroll
  for (int ks = 0; ks < C32 / 32; ++ks)
    base = mfma_h(ldfragH<RB>(CtrB, m15, ks * 32 + kb8), bc[ks], base);

  f32x4 mx = {-FLT_MAX, -FLT_MAX, -FLT_MAX, -FLT_MAX};
#pragma unroll
  for (int k = 0; k < TK; ++k) {
    f32x4 a = {0, 0, 0, 0};
#pragma unroll
    for (int ks = 0; ks < C32 / 32; ++ks)
      a = mfma_h(ldfragH<RB>(A1, 16 * k + m15, ks * 32 + kb8), bd[ks], a);
#pragma unroll
    for (int r = 0; r < 4; ++r) mx[r] = fmaxf(mx[r], a[r] + base[r]);
  }

  const int o = 16 * w + m15;
  const float scv = gam[o] / sqrtf(var[o] + 1e-5f);
  const float shv = bet[o] - mea[o] * scv;
#pragma unroll
  for (int r = 0; r < 4; ++r) {
    const int n = (lane >> 4) * 4 + r;
    float v = scv * mx[r] + shv;
    v = (v >= 0.f) ? v : 0.2f * v;
    y[((size_t)b * N + n0 + n) * O + o] = v;
  }
}

// ---------------- attention pooling ----------------
// partial row-sums -> atomicAdd into msum[b][f]
__global__ __launch_bounds__(256)
void att_mean_kernel(const float* __restrict__ emb, float* __restrict__ msum) {
  constexpr int N = 2048, F = 64;
  const int b    = blockIdx.x >> 4;
  const int slab = blockIdx.x & 15;          // 128 rows per slab
  const int tid  = threadIdx.x;
  const int f = tid & 63, p = tid >> 6;
  __shared__ float part[4][F];
  float acc = 0.f;
  const float* e = emb + ((size_t)b * N + slab * 128) * F;
  for (int n = p; n < 128; n += 4) acc += e[(size_t)n * F + f];
  part[p][f] = acc;
  __syncthreads();
  if (tid < F)
    atomicAdd(&msum[b * F + tid],
              part[0][tid] + part[1][tid] + part[2][tid] + part[3][tid]);
}

__global__ __launch_bounds__(64)
void att_ctx_kernel(const float* __restrict__ msum, const float* __restrict__ Watt,
                    float* __restrict__ ctx) {
  constexpr int N = 2048, F = 64;
  const int b = blockIdx.x, tid = threadIdx.x;
  __shared__ float m[F];
  m[tid] = msum[b * F + tid] * (1.f / N);
  __syncthreads();
  float a = 0.f;
  for (int ff = 0; ff < F; ++ff) a += m[ff] * Watt[ff * F + tid];
  ctx[b * F + tid] = tanhf(a);
}

__global__ __launch_bounds__(256)
void att2_kernel(const float* __restrict__ emb, const float* __restrict__ ctx,
                 float* __restrict__ eout) {
  constexpr int N = 2048, F = 64;
  const int b   = blockIdx.x >> 3;
  const int c0  = (blockIdx.x & 7) * 256;
  const int tid = threadIdx.x, lane = tid & 63, w = tid >> 6;
  const float cv = ctx[b * F + lane];
  float acc = 0.f;
  const float* e = emb + (size_t)b * N * F;
  for (int n = c0 + w * 64; n < c0 + (w + 1) * 64; ++n) {
    const float v = e[(size_t)n * F + lane];
    float d = v * cv;
#pragma unroll
    for (int off = 1; off < 64; off <<= 1) d += __shfl_xor(d, off);
    const float s = 1.f / (1.f + expf(-d));
    acc += v * s;
  }
  atomicAdd(&eout[b * F + lane], acc);
}

// ---------------- tensor network ----------------
__global__ __launch_bounds__(256)
void tn_kernel(const float* __restrict__ e1, const float* __restrict__ e2,
               const float* __restrict__ Wt, const float* __restrict__ Wb,
               const float* __restrict__ bias, float* __restrict__ out) {
  constexpr int F = 64, T = 16;
  const int b = blockIdx.x, tid = threadIdx.x;
  __shared__ float s1[F], s2[F];
  __shared__ float part[T][17];
  if (tid < F) { s1[tid] = e1[b * F + tid]; s2[tid] = e2[b * F + tid]; }
  __syncthreads();
  const int t = tid >> 4, sub = tid & 15;
  float a = 0.f;
  for (int f = sub * 4; f < sub * 4 + 4; ++f) {
    float inner = 0.f;
    for (int g = 0; g < F; ++g) inner += Wt[((f * F) + g) * T + t] * s2[g];
    a += s1[f] * inner;
  }
  part[t][sub] = a;
  __syncthreads();
  if (tid < T) {
    float v = 0.f;
    for (int q = 0; q < 16; ++q) v += part[tid][q];
    for (int f = 0; f < F; ++f)
      v += Wb[tid * 2 * F + f] * s1[f] + Wb[tid * 2 * F + F + f] * s2[f];
    v += bias[tid];
    out[b * T + tid] = fmaxf(v, 0.f);
  }
}

extern "C" void kernel_launch(void* const* d_in, const int* in_sizes, int n_in,
                              void* d_out, int out_size, void* d_ws, size_t ws_size,
                              hipStream_t stream) {
  const float* x1  = (const float*)d_in[0];
  const float* x2  = (const float*)d_in[1];
  const float* W1  = (const float*)d_in[2];
  const float* g1  = (const float*)d_in[3];
  const float* b1  = (const float*)d_in[4];
  const float* m1  = (const float*)d_in[5];
  const float* v1  = (const float*)d_in[6];
  const float* W2  = (const float*)d_in[7];
  const float* g2  = (const float*)d_in[8];
  const float* b2  = (const float*)d_in[9];
  const float* m2  = (const float*)d_in[10];
  const float* v2  = (const float*)d_in[11];
  const float* W3  = (const float*)d_in[12];
  const float* g3  = (const float*)d_in[13];
  const float* b3  = (const float*)d_in[14];
  const float* m3  = (const float*)d_in[15];
  const float* v3  = (const float*)d_in[16];
  const float* Wat = (const float*)d_in[17];
  const float* Wt  = (const float*)d_in[18];
  const float* Wb  = (const float*)d_in[19];
  const float* bs  = (const float*)d_in[20];
  float* out = (float*)d_out;

  float* buf1 = (float*)d_ws;
  float* buf2 = buf1 + (size_t)8 * 2048 * 64;
  float* buf3 = buf2 + (size_t)8 * 2048 * 64;
  float* sqb  = buf3 + (size_t)8 * 2048 * 64;
  int*   idxb = (int*)(sqb + 8 * 2048);
  float* ctx1 = (float*)(idxb + (size_t)8 * 2048 * 20);
  float* ctx2 = ctx1 + 512;
  float* e1   = ctx2 + 512;   // e1, e2, ms1, ms2 contiguous -> one memset
  float* e2   = e1 + 512;
  float* ms1  = e2 + 512;
  float* ms2  = ms1 + 512;

  auto run_graph = [&](const float* xin, float* t1, float* t2) {
    sq_kernel<12><<<64, 256, 0, stream>>>(xin, sqb);
    knn_kernel<12, 32><<<256, 1024, 0, stream>>>(xin, sqb, idxb);
    conv_kernel<12, 32><<<1024, 256, 0, stream>>>(xin, idxb, W1, g1, b1, m1, v1, t1);

    sq_kernel<64><<<64, 256, 0, stream>>>(t1, sqb);
    knn_kernel<64, 64><<<256, 1024, 0, stream>>>(t1, sqb, idxb);
    conv_kernel<64, 64><<<1024, 256, 0, stream>>>(t1, idxb, W2, g2, b2, m2, v2, t2);

    sq_kernel<64><<<64, 256, 0, stream>>>(t2, sqb);
    knn_kernel<64, 64><<<256, 1024, 0, stream>>>(t2, sqb, idxb);
    conv_kernel<64, 64><<<1024, 256, 0, stream>>>(t2, idxb, W3, g3, b3, m3, v3, t1);
  };

  run_graph(x1, buf1, buf3);  // emb1 = buf1
  run_graph(x2, buf2, buf3);  // emb2 = buf2

  hipMemsetAsync(e1, 0, 4 * 512 * sizeof(float), stream);  // e1,e2,ms1,ms2
  att_mean_kernel<<<128, 256, 0, stream>>>(buf1, ms1);
  att_mean_kernel<<<128, 256, 0, stream>>>(buf2, ms2);
  att_ctx_kernel<<<8, 64, 0, stream>>>(ms1, Wat, ctx1);
  att_ctx_kernel<<<8, 64, 0, stream>>>(ms2, Wat, ctx2);
  att2_kernel<<<64, 256, 0, stream>>>(buf1, ctx1, e1);
  att2_kernel<<<64, 256, 0, stream>>>(buf2, ctx2, e2);
  tn_kernel<<<8, 256, 0, stream>>>(e1, e2, Wt, Wb, bs, out);
}

// Round 7
// 1001.082 us; speedup vs baseline: 1.6450x; 1.6450x over previous
//
#include <hip/hip_runtime.h>
#include <hip/hip_bf16.h>
#include <float.h>

#define DEV __device__ __forceinline__

using f32x4 = __attribute__((ext_vector_type(4))) float;
using f4v   = __attribute__((ext_vector_type(4))) float;
using bfrag = __attribute__((ext_vector_type(8))) short;     // 8 bf16
using hfrag = __attribute__((ext_vector_type(8))) _Float16;  // 8 f16
using us8   = __attribute__((ext_vector_type(8))) unsigned short;

DEV unsigned short f2bf(float f) {
  unsigned u = __builtin_bit_cast(unsigned, f);
  u += 0x7FFFu + ((u >> 16) & 1u);
  return (unsigned short)(u >> 16);
}
DEV float bf2f(unsigned short h) {
  unsigned u = ((unsigned)h) << 16;
  return __builtin_bit_cast(float, u);
}
DEV f32x4 mfma_bf(bfrag a, bfrag b, f32x4 c) {
  return __builtin_amdgcn_mfma_f32_16x16x32_bf16(a, b, c, 0, 0, 0);
}
DEV f32x4 mfma_h(hfrag a, hfrag b, f32x4 c) {
  return __builtin_amdgcn_mfma_f32_16x16x32_f16(a, b, c, 0, 0, 0);
}
DEV float readlane_f(float v, int l) {
  return __builtin_bit_cast(float,
      __builtin_amdgcn_readlane(__builtin_bit_cast(int, v), l));
}

// XOR-swizzled LDS byte offset for row-major tiles of RB bytes/row (T2 pattern)
template<int RB>
DEV unsigned swz(int row, int colb) {
  return (unsigned)(row * RB) +
         (((unsigned)colb) ^ (((unsigned)(row << 4)) & (unsigned)(RB - 1)));
}
template<int RB>
DEV bfrag ldfragB(const unsigned short* base, int row, int kcol) {
  return *(const bfrag*)((const char*)base + swz<RB>(row, kcol * 2));
}
template<int RB>
DEV hfrag ldfragH(const _Float16* base, int row, int kcol) {
  return *(const hfrag*)((const char*)base + swz<RB>(row, kcol * 2));
}

// stage 64 rows of C floats -> bf16 hi/lo LDS tiles [64][C32], one 8-col chunk
// per thread (threads >= 64*C32/8 idle)
template<int C, int C32>
DEV void stageHL(const float* __restrict__ src, unsigned short* H,
                 unsigned short* L, int tid) {
  constexpr int RB  = C32 * 2;
  constexpr int CH8 = C32 / 8;
  if (tid < 64 * CH8) {
    const int row = tid / CH8, cb = (tid % CH8) * 8;
    float f[8];
    if constexpr (C % 8 == 0) {
      *(f4v*)(f + 0) = *(const f4v*)(src + row * C + cb);
      *(f4v*)(f + 4) = *(const f4v*)(src + row * C + cb + 4);
    } else {
#pragma unroll
      for (int e = 0; e < 8; ++e) {
        const int c = cb + e;
        f[e] = (c < C) ? src[row * C + c] : 0.f;
      }
    }
    us8 hv, lv;
#pragma unroll
    for (int e = 0; e < 8; ++e) {
      const unsigned short hs = f2bf(f[e]);
      hv[e] = hs;
      lv[e] = f2bf(f[e] - bf2f(hs));
    }
    const unsigned off = swz<RB>(row, cb * 2);
    *(us8*)((char*)H + off) = hv;
    *(us8*)((char*)L + off) = lv;
  }
}

// full-wave bitonic sort, descending by value, ties ascending by index
DEV void bitonic64(float& v, int& ix, int lane) {
#pragma unroll
  for (int k = 2; k <= 64; k <<= 1) {
#pragma unroll
    for (int j = k >> 1; j > 0; j >>= 1) {
      const float ov = __shfl_xor(v, j);
      const int   oi = __shfl_xor(ix, j);
      const bool up = (lane & k) != 0;
      const bool iWin = (v > ov) || (v == ov && ix < oi);
      const bool keepBetter = (((lane & j) == 0) != up);
      if (iWin != keepBetter) { v = ov; ix = oi; }
    }
  }
}

// batch selector: b in 0..15 -> graph1 (xA) batches 0..7, graph2 (xB) 8..15
template<int C>
DEV const float* xbase(const float* xA, const float* xB, int b) {
  return (b < 8) ? xA + (size_t)b * 2048 * C
                 : xB + (size_t)(b - 8) * 2048 * C;
}

// ---------------- squared norms (16 batches, pair input) ----------------
template<int C>
__global__ __launch_bounds__(256)
void sq_kernel(const float* __restrict__ xA, const float* __restrict__ xB,
               float* __restrict__ sq) {
  const int i = blockIdx.x * 256 + threadIdx.x;   // 0 .. 16*2048-1
  const int b = i >> 11, n = i & 2047;
  const float* r = xbase<C>(xA, xB, b) + (size_t)n * C;
  float s = 0.f;
#pragma unroll
  for (int c = 0; c < C; c += 4) {
    f4v v = *(const f4v*)(r + c);
    s += v[0] * v[0] + v[1] * v[1] + v[2] * v[2] + v[3] * v[3];
  }
  sq[i] = s;
}

// ---------------- fused kNN: 1024 threads, 16 waves, 4 rows/wave ----------------
// grid: b(16) x i-tile(32) = 512 blocks. Single sweep, insert-based selection
// with readlane broadcasts + deferred threshold update (2 DS ops/insert).
template<int C, int C32>
__global__ __launch_bounds__(1024)
void knn_kernel(const float* __restrict__ xA, const float* __restrict__ xB,
                const float* __restrict__ sqg, int* __restrict__ idx_out) {
  constexpr int N = 2048, TI = 64, TJ = 64, TK = 20, NT = N / TJ;
  constexpr int RB = C32 * 2;
  const int b    = blockIdx.x >> 5;        // 0..15
  const int i0   = (blockIdx.x & 31) * TI;
  const int tid  = threadIdx.x;
  const int lane = tid & 63;
  const int w    = tid >> 6;               // 0..15
  const int ri   = w >> 2;                 // MFMA quadrant row
  const int ci   = w & 3;                  // MFMA quadrant col

  __shared__ unsigned short XiH[TI * C32], XiL[TI * C32];
  __shared__ unsigned short XjH[TJ * C32], XjL[TJ * C32];
  __shared__ float S[TI][TJ + 4];
  __shared__ float sqT[TJ];

  const float* xb = xbase<C>(xA, xB, b);
  const int m15 = lane & 15;
  const int kb8 = (lane >> 4) * 8;

  stageHL<C, C32>(xb + (size_t)i0 * C, XiH, XiL, tid);

  float tv[4], t20[4]; int tix[4];
#pragma unroll
  for (int d = 0; d < 4; ++d) { tv[d] = -FLT_MAX; tix[d] = 0; t20[d] = -FLT_MAX; }

  for (int jt = 0; jt < NT; ++jt) {
    const int j0 = jt * TJ;
    stageHL<C, C32>(xb + (size_t)j0 * C, XjH, XjL, tid);
    if (tid < TJ) sqT[tid] = sqg[b * N + j0 + tid];
    __syncthreads();   // Xj/sqT staged; prev-tile selection (reads S) done

    f32x4 acc = {0, 0, 0, 0};
#pragma unroll
    for (int ks = 0; ks < C32 / 32; ++ks) {
      const int kc = ks * 32 + kb8;
      const bfrag ah = ldfragB<RB>(XiH, 16 * ri + m15, kc);
      const bfrag al = ldfragB<RB>(XiL, 16 * ri + m15, kc);
      const bfrag bh = ldfragB<RB>(XjH, 16 * ci + m15, kc);
      const bfrag bl = ldfragB<RB>(XjL, 16 * ci + m15, kc);
      acc = mfma_bf(ah, bh, acc);
      acc = mfma_bf(ah, bl, acc);
      acc = mfma_bf(al, bh, acc);
    }
#pragma unroll
    for (int r = 0; r < 4; ++r)
      S[16 * ri + (lane >> 4) * 4 + r][16 * ci + m15] = acc[r];
    const float sqv = sqT[lane];   // hoisted: safe between the two barriers
    __syncthreads();   // S complete

#pragma unroll
    for (int d = 0; d < 4; ++d) {
      const float sc = 2.f * S[4 * w + d][lane] - sqv;
      if (jt == 0) {
        float v = sc; int ixv = lane;    // j0 == 0
        bitonic64(v, ixv, lane);
        tv[d]  = (lane < TK) ? v : -FLT_MAX;
        tix[d] = (lane < TK) ? ixv : 0;
        t20[d] = readlane_f(tv[d], TK - 1);
      } else {
        unsigned long long mm = __ballot(sc > t20[d]);
        if (mm) {
          while (mm) {
            const int src = __ffsll(mm) - 1;
            mm &= mm - 1;
            const float cv = readlane_f(sc, src);
            const int   ci2 = j0 + src;
            const float pv_ = __shfl_up(tv[d], 1);
            const int   pi_ = __shfl_up(tix[d], 1);
            const unsigned long long g =
                __ballot(tv[d] > cv || (tv[d] == cv && tix[d] < ci2));
            const int p = __popcll(g);     // wave-uniform
            float nv = (lane == p) ? cv  : ((lane > p) ? pv_ : tv[d]);
            int   ni = (lane == p) ? ci2 : ((lane > p) ? pi_ : tix[d]);
            tv[d]  = (lane >= TK) ? -FLT_MAX : nv;
            tix[d] = (lane >= TK) ? 0 : ni;
          }
          t20[d] = readlane_f(tv[d], TK - 1);  // refresh once per tile
        }
      }
    }
  }
  if (lane < TK) {
#pragma unroll
    for (int d = 0; d < 4; ++d) {
      const int i = i0 + 4 * w + d;
      idx_out[((size_t)b * N + i) * TK + lane] = tix[d];
    }
  }
}

// ---------------- edgeconv: gather + fp16 MFMA + BN + LeakyReLU + max_k --------
// grid: b(16) x n-tile(128) = 2048 blocks; y contiguous [16][2048][64]
template<int C, int C32>
__global__ __launch_bounds__(256)
void conv_kernel(const float* __restrict__ xA, const float* __restrict__ xB,
                 const int* __restrict__ idxg,
                 const float* __restrict__ W, const float* __restrict__ gam,
                 const float* __restrict__ bet, const float* __restrict__ mea,
                 const float* __restrict__ var, float* __restrict__ y) {
  constexpr int N = 2048, TK = 20, O = 64;
  constexpr int RB = C32 * 2;
  constexpr int CH8 = C32 / 8;
  const int b    = blockIdx.x >> 7;        // 0..15
  const int n0   = (blockIdx.x & 127) * 16;
  const int tid  = threadIdx.x;
  const int lane = tid & 63;
  const int w    = tid >> 6;

  __shared__ float    ctrF[16][C];
  __shared__ _Float16 A1[320 * C32];
  __shared__ _Float16 CtrB[16 * C32];
  __shared__ _Float16 WdT[O * C32];
  __shared__ _Float16 WcT[O * C32];

  const float* xb = xbase<C>(xA, xB, b);

  for (int i = tid; i < 16 * C; i += 256)
    ctrF[i / C][i % C] = xb[(size_t)(n0 + i / C) * C + (i % C)];

  for (int i = tid; i < O * CH8; i += 256) {
    const int o = i / CH8, ch = (i % CH8) * 8;
    hfrag hd, hc;
#pragma unroll
    for (int e = 0; e < 8; ++e) {
      const int c = ch + e;
      hd[e] = (c < C) ? (_Float16)W[o * 2 * C + c]     : (_Float16)0.f;
      hc[e] = (c < C) ? (_Float16)W[o * 2 * C + C + c] : (_Float16)0.f;
    }
    const unsigned off = swz<RB>(o, ch * 2);
    *(hfrag*)((char*)WdT + off) = hd;
    *(hfrag*)((char*)WcT + off) = hc;
  }
  __syncthreads();

  for (int i = tid; i < 16 * CH8; i += 256) {
    const int row = i / CH8, ch = (i % CH8) * 8;
    hfrag hv;
#pragma unroll
    for (int e = 0; e < 8; ++e) {
      const int c = ch + e;
      hv[e] = (c < C) ? (_Float16)ctrF[row][c] : (_Float16)0.f;
    }
    *(hfrag*)((char*)CtrB + swz<RB>(row, ch * 2)) = hv;
  }

  for (int r = tid; r < 16 * TK; r += 256) {
    const int n = r & 15, k = r >> 4;
    int j = idxg[((size_t)b * N + n0 + n) * TK + k];
    j &= (N - 1);  // safety clamp
    const float* xj = xb + (size_t)j * C;
#pragma unroll
    for (int ch = 0; ch < C32; ch += 8) {
      float f[8];
#pragma unroll
      for (int q = 0; q < 8; q += 4) {
        const int c = ch + q;
        if (c + 3 < C) {
          *(f4v*)(f + q) = *(const f4v*)(xj + c);
        } else {
#pragma unroll
          for (int e = 0; e < 4; ++e) f[q + e] = (c + e < C) ? xj[c + e] : 0.f;
        }
      }
      hfrag hv;
#pragma unroll
      for (int e = 0; e < 8; ++e) {
        const int c = ch + e;
        const float d = (c < C) ? (f[e] - ctrF[n][c]) : 0.f;
        hv[e] = (_Float16)d;
      }
      *(hfrag*)((char*)A1 + swz<RB>(r, ch * 2)) = hv;
    }
  }
  __syncthreads();

  const int m15 = lane & 15;
  const int kb8 = (lane >> 4) * 8;
  hfrag bd[C32 / 32], bc[C32 / 32];
#pragma unroll
  for (int ks = 0; ks < C32 / 32; ++ks) {
    bd[ks] = ldfragH<RB>(WdT, 16 * w + m15, ks * 32 + kb8);
    bc[ks] = ldfragH<RB>(WcT, 16 * w + m15, ks * 32 + kb8);
  }
  f32x4 base = {0, 0, 0, 0};
#pragma unroll
  for (int ks = 0; ks < C32 / 32; ++ks)
    base = mfma_h(ldfragH<RB>(CtrB, m15, ks * 32 + kb8), bc[ks], base);

  f32x4 mx = {-FLT_MAX, -FLT_MAX, -FLT_MAX, -FLT_MAX};
#pragma unroll
  for (int k = 0; k < TK; ++k) {
    f32x4 a = {0, 0, 0, 0};
#pragma unroll
    for (int ks = 0; ks < C32 / 32; ++ks)
      a = mfma_h(ldfragH<RB>(A1, 16 * k + m15, ks * 32 + kb8), bd[ks], a);
#pragma unroll
    for (int r = 0; r < 4; ++r) mx[r] = fmaxf(mx[r], a[r] + base[r]);
  }

  const int o = 16 * w + m15;
  const float scv = gam[o] / sqrtf(var[o] + 1e-5f);
  const float shv = bet[o] - mea[o] * scv;
#pragma unroll
  for (int r = 0; r < 4; ++r) {
    const int n = (lane >> 4) * 4 + r;
    float v = scv * mx[r] + shv;
    v = (v >= 0.f) ? v : 0.2f * v;
    y[((size_t)b * N + n0 + n) * O + o] = v;
  }
}

// ---------------- attention pooling (16 batches, contiguous emb) -------------
__global__ __launch_bounds__(256)
void att_mean_kernel(const float* __restrict__ emb, float* __restrict__ msum) {
  constexpr int N = 2048, F = 64;
  const int b    = blockIdx.x >> 4;          // 0..15
  const int slab = blockIdx.x & 15;          // 128 rows per slab
  const int tid  = threadIdx.x;
  const int f = tid & 63, p = tid >> 6;
  __shared__ float part[4][F];
  float acc = 0.f;
  const float* e = emb + ((size_t)b * N + slab * 128) * F;
  for (int n = p; n < 128; n += 4) acc += e[(size_t)n * F + f];
  part[p][f] = acc;
  __syncthreads();
  if (tid < F)
    atomicAdd(&msum[b * F + tid],
              part[0][tid] + part[1][tid] + part[2][tid] + part[3][tid]);
}

__global__ __launch_bounds__(64)
void att_ctx_kernel(const float* __restrict__ msum, const float* __restrict__ Watt,
                    float* __restrict__ ctx) {
  constexpr int N = 2048, F = 64;
  const int b = blockIdx.x, tid = threadIdx.x;
  __shared__ float m[F];
  m[tid] = msum[b * F + tid] * (1.f / N);
  __syncthreads();
  float a = 0.f;
  for (int ff = 0; ff < F; ++ff) a += m[ff] * Watt[ff * F + tid];
  ctx[b * F + tid] = tanhf(a);
}

__global__ __launch_bounds__(256)
void att2_kernel(const float* __restrict__ emb, const float* __restrict__ ctx,
                 float* __restrict__ eout) {
  constexpr int N = 2048, F = 64;
  const int b   = blockIdx.x >> 3;           // 0..15
  const int c0  = (blockIdx.x & 7) * 256;
  const int tid = threadIdx.x, lane = tid & 63, w = tid >> 6;
  const float cv = ctx[b * F + lane];
  float acc = 0.f;
  const float* e = emb + (size_t)b * N * F;
  for (int n = c0 + w * 64; n < c0 + (w + 1) * 64; ++n) {
    const float v = e[(size_t)n * F + lane];
    float d = v * cv;
#pragma unroll
    for (int off = 1; off < 64; off <<= 1) d += __shfl_xor(d, off);
    const float s = 1.f / (1.f + expf(-d));
    acc += v * s;
  }
  atomicAdd(&eout[b * F + lane], acc);
}

// ---------------- tensor network ----------------
__global__ __launch_bounds__(256)
void tn_kernel(const float* __restrict__ ep,
               const float* __restrict__ Wt, const float* __restrict__ Wb,
               const float* __restrict__ bias, float* __restrict__ out) {
  constexpr int F = 64, T = 16;
  const int b = blockIdx.x, tid = threadIdx.x;
  __shared__ float s1[F], s2[F];
  __shared__ float part[T][17];
  if (tid < F) { s1[tid] = ep[b * F + tid]; s2[tid] = ep[(b + 8) * F + tid]; }
  __syncthreads();
  const int t = tid >> 4, sub = tid & 15;
  float a = 0.f;
  for (int f = sub * 4; f < sub * 4 + 4; ++f) {
    float inner = 0.f;
    for (int g = 0; g < F; ++g) inner += Wt[((f * F) + g) * T + t] * s2[g];
    a += s1[f] * inner;
  }
  part[t][sub] = a;
  __syncthreads();
  if (tid < T) {
    float v = 0.f;
    for (int q = 0; q < 16; ++q) v += part[tid][q];
    for (int f = 0; f < F; ++f)
      v += Wb[tid * 2 * F + f] * s1[f] + Wb[tid * 2 * F + F + f] * s2[f];
    v += bias[tid];
    out[b * T + tid] = fmaxf(v, 0.f);
  }
}

extern "C" void kernel_launch(void* const* d_in, const int* in_sizes, int n_in,
                              void* d_out, int out_size, void* d_ws, size_t ws_size,
                              hipStream_t stream) {
  const float* x1  = (const float*)d_in[0];
  const float* x2  = (const float*)d_in[1];
  const float* W1  = (const float*)d_in[2];
  const float* g1  = (const float*)d_in[3];
  const float* b1  = (const float*)d_in[4];
  const float* m1  = (const float*)d_in[5];
  const float* v1  = (const float*)d_in[6];
  const float* W2  = (const float*)d_in[7];
  const float* g2  = (const float*)d_in[8];
  const float* b2  = (const float*)d_in[9];
  const float* m2  = (const float*)d_in[10];
  const float* v2  = (const float*)d_in[11];
  const float* W3  = (const float*)d_in[12];
  const float* g3  = (const float*)d_in[13];
  const float* b3  = (const float*)d_in[14];
  const float* m3  = (const float*)d_in[15];
  const float* v3  = (const float*)d_in[16];
  const float* Wat = (const float*)d_in[17];
  const float* Wt  = (const float*)d_in[18];
  const float* Wb  = (const float*)d_in[19];
  const float* bs  = (const float*)d_in[20];
  float* out = (float*)d_out;

  constexpr size_t NF = (size_t)16 * 2048 * 64;   // 16 batches (both graphs)
  float* bufA = (float*)d_ws;
  float* bufB = bufA + NF;
  float* sqb  = bufB + NF;                        // 16*2048
  int*   idxb = (int*)(sqb + 16 * 2048);          // 16*2048*20
  float* msum = (float*)(idxb + (size_t)16 * 2048 * 20);  // 16*64
  float* epool= msum + 16 * 64;                   // 16*64
  float* ctx  = epool + 16 * 64;                  // 16*64

  const float* bA8 = bufA + (size_t)8 * 2048 * 64;
  const float* bB8 = bufB + (size_t)8 * 2048 * 64;

  // layer 1: x(pair) -> bufA
  sq_kernel<12><<<128, 256, 0, stream>>>(x1, x2, sqb);
  knn_kernel<12, 32><<<512, 1024, 0, stream>>>(x1, x2, sqb, idxb);
  conv_kernel<12, 32><<<2048, 256, 0, stream>>>(x1, x2, idxb, W1, g1, b1, m1, v1, bufA);

  // layer 2: bufA -> bufB
  sq_kernel<64><<<128, 256, 0, stream>>>(bufA, bA8, sqb);
  knn_kernel<64, 64><<<512, 1024, 0, stream>>>(bufA, bA8, sqb, idxb);
  conv_kernel<64, 64><<<2048, 256, 0, stream>>>(bufA, bA8, idxb, W2, g2, b2, m2, v2, bufB);

  // layer 3: bufB -> bufA (= final emb, 16 batches)
  sq_kernel<64><<<128, 256, 0, stream>>>(bufB, bB8, sqb);
  knn_kernel<64, 64><<<512, 1024, 0, stream>>>(bufB, bB8, sqb, idxb);
  conv_kernel<64, 64><<<2048, 256, 0, stream>>>(bufB, bB8, idxb, W3, g3, b3, m3, v3, bufA);

  hipMemsetAsync(msum, 0, 2 * 16 * 64 * sizeof(float), stream);  // msum+epool
  att_mean_kernel<<<256, 256, 0, stream>>>(bufA, msum);
  att_ctx_kernel<<<16, 64, 0, stream>>>(msum, Wat, ctx);
  att2_kernel<<<128, 256, 0, stream>>>(bufA, ctx, epool);
  tn_kernel<<<8, 256, 0, stream>>>(epool, Wt, Wb, bs, out);
}

// Round 8
// 937.387 us; speedup vs baseline: 1.7567x; 1.0680x over previous
//
#include <hip/hip_runtime.h>
#include <hip/hip_bf16.h>
#include <float.h>

#define DEV __device__ __forceinline__

using f32x4 = __attribute__((ext_vector_type(4))) float;
using f4v   = __attribute__((ext_vector_type(4))) float;
using bfrag = __attribute__((ext_vector_type(8))) short;     // 8 bf16
using hfrag = __attribute__((ext_vector_type(8))) _Float16;  // 8 f16
using us8   = __attribute__((ext_vector_type(8))) unsigned short;

DEV unsigned short f2bf(float f) {
  unsigned u = __builtin_bit_cast(unsigned, f);
  u += 0x7FFFu + ((u >> 16) & 1u);
  return (unsigned short)(u >> 16);
}
DEV float bf2f(unsigned short h) {
  unsigned u = ((unsigned)h) << 16;
  return __builtin_bit_cast(float, u);
}
DEV f32x4 mfma_bf(bfrag a, bfrag b, f32x4 c) {
  return __builtin_amdgcn_mfma_f32_16x16x32_bf16(a, b, c, 0, 0, 0);
}
DEV f32x4 mfma_h(hfrag a, hfrag b, f32x4 c) {
  return __builtin_amdgcn_mfma_f32_16x16x32_f16(a, b, c, 0, 0, 0);
}
DEV float readlane_f(float v, int l) {
  return __builtin_bit_cast(float,
      __builtin_amdgcn_readlane(__builtin_bit_cast(int, v), l));
}

// XOR-swizzled LDS byte offset for row-major tiles of RB bytes/row (T2 pattern)
template<int RB>
DEV unsigned swz(int row, int colb) {
  return (unsigned)(row * RB) +
         (((unsigned)colb) ^ (((unsigned)(row << 4)) & (unsigned)(RB - 1)));
}
template<int RB>
DEV bfrag ldfragB(const unsigned short* base, int row, int kcol) {
  return *(const bfrag*)((const char*)base + swz<RB>(row, kcol * 2));
}
template<int RB>
DEV hfrag ldfragH(const _Float16* base, int row, int kcol) {
  return *(const hfrag*)((const char*)base + swz<RB>(row, kcol * 2));
}

// 16B-per-thread copy, 512-thread block
template<int BYTES>
DEV void cpyN(const char* __restrict__ g, char* __restrict__ l, int tid) {
  if constexpr (BYTES >= 8192) {
#pragma unroll
    for (int o = 0; o < BYTES; o += 8192)
      *(us8*)(l + o + tid * 16) = *(const us8*)(g + o + tid * 16);
  } else {
    const int o = tid * 16;
    if (o < BYTES) *(us8*)(l + o) = *(const us8*)(g + o);
  }
}

// full-wave bitonic sort, descending by value, ties ascending by index
DEV void bitonic64(float& v, int& ix, int lane) {
#pragma unroll
  for (int k = 2; k <= 64; k <<= 1) {
#pragma unroll
    for (int j = k >> 1; j > 0; j >>= 1) {
      const float ov = __shfl_xor(v, j);
      const int   oi = __shfl_xor(ix, j);
      const bool up = (lane & k) != 0;
      const bool iWin = (v > ov) || (v == ov && ix < oi);
      const bool keepBetter = (((lane & j) == 0) != up);
      if (iWin != keepBetter) { v = ov; ix = oi; }
    }
  }
}

// batch selector: b in 0..15 -> graph1 (xA) batches 0..7, graph2 (xB) 8..15
template<int C>
DEV const float* xbase(const float* xA, const float* xB, int b) {
  return (b < 8) ? xA + (size_t)b * 2048 * C
                 : xB + (size_t)(b - 8) * 2048 * C;
}

// ---------------- squared norms (16 batches, pair input) ----------------
template<int C>
__global__ __launch_bounds__(256)
void sq_kernel(const float* __restrict__ xA, const float* __restrict__ xB,
               float* __restrict__ sq) {
  const int i = blockIdx.x * 256 + threadIdx.x;   // 0 .. 16*2048-1
  const int b = i >> 11, n = i & 2047;
  const float* r = xbase<C>(xA, xB, b) + (size_t)n * C;
  float s = 0.f;
#pragma unroll
  for (int c = 0; c < C; c += 4) {
    f4v v = *(const f4v*)(r + c);
    s += v[0] * v[0] + v[1] * v[1] + v[2] * v[2] + v[3] * v[3];
  }
  sq[i] = s;
}

// ---------------- one-time fp32 -> bf16 hi/lo pre-swizzled tile images --------
// layout: [b(16)][tile(32)][ H: 64 rows x C32 bf16 swizzled | L: same ]
template<int C, int C32>
__global__ __launch_bounds__(256)
void cvt_kernel(const float* __restrict__ xA, const float* __restrict__ xB,
                char* __restrict__ xhl) {
  constexpr int CH8 = C32 / 8, RB = C32 * 2, HB = 64 * RB;
  const int idx = blockIdx.x * 256 + threadIdx.x;
  const int chunk = idx & (CH8 - 1);
  const int rg = idx / CH8;
  const int b = rg >> 11, n = rg & 2047;
  const float* src = xbase<C>(xA, xB, b) + (size_t)n * C;
  const int cb = chunk * 8;
  float f[8];
  if constexpr (C % 8 == 0) {
    *(f4v*)(f + 0) = *(const f4v*)(src + cb);
    *(f4v*)(f + 4) = *(const f4v*)(src + cb + 4);
  } else {
#pragma unroll
    for (int e = 0; e < 8; ++e) {
      const int c = cb + e;
      f[e] = (c < C) ? src[c] : 0.f;
    }
  }
  us8 hv, lv;
#pragma unroll
  for (int e = 0; e < 8; ++e) {
    const unsigned short hs = f2bf(f[e]);
    hv[e] = hs;
    lv[e] = f2bf(f[e] - bf2f(hs));
  }
  char* dst = xhl + (size_t)(b * 32 + (n >> 6)) * 2 * HB;
  const unsigned off = swz<RB>(n & 63, cb * 2);
  *(us8*)(dst + off) = hv;
  *(us8*)(dst + HB + off) = lv;
}

// ---------------- fused kNN: 512 threads, 8 waves, 32 i-rows/block -------------
// grid: b(16) x i-tile(64, 32 rows each) = 1024 blocks -> 4 blocks/CU.
// Staging = pure 16B copies of pre-converted tile images (no VALU convert).
// Selection identical to R7 (readlane broadcasts, deferred threshold).
template<int C32>
__global__ __launch_bounds__(512)
void knn_kernel(const char* __restrict__ xhl, const float* __restrict__ sqg,
                int* __restrict__ idx_out) {
  constexpr int N = 2048, TI = 32, TJ = 64, TK = 20, NT = N / TJ;
  constexpr int RB = C32 * 2, HB = 64 * RB, TILEB = 2 * HB, HBi = TI * RB;
  const int b    = blockIdx.x >> 6;        // 0..15
  const int it   = blockIdx.x & 63;        // 32-row tile
  const int i0   = it * TI;
  const int tid  = threadIdx.x;
  const int lane = tid & 63;
  const int w    = tid >> 6;               // 0..7
  const int ri   = w >> 2;                 // 0..1
  const int ci   = w & 3;                  // 0..3

  __shared__ us8 XiV[2 * HBi / 16];
  __shared__ us8 XjV[TILEB / 16];
  __shared__ float S[TI][TJ + 4];
  __shared__ float sqT[TJ];

  char* XiC = (char*)XiV;
  char* XjC = (char*)XjV;
  const unsigned short* XiHp = (const unsigned short*)XiC;
  const unsigned short* XiLp = (const unsigned short*)(XiC + HBi);
  const unsigned short* XjHp = (const unsigned short*)XjC;
  const unsigned short* XjLp = (const unsigned short*)(XjC + HB);
  const int m15 = lane & 15, kb8 = (lane >> 4) * 8;

  // Xi slice: rows (i0&63)..+31 of 64-row tile (i0>>6); swizzle is row-local,
  // rows are contiguous RB-byte spans -> slice is contiguous.
  const char* gti = xhl + (size_t)(b * 32 + (i0 >> 6)) * TILEB + (i0 & 63) * RB;
  cpyN<HBi>(gti, XiC, tid);            // H slice
  cpyN<HBi>(gti + HB, XiC + HBi, tid); // L slice

  float tv[4], t20[4]; int tix[4];
#pragma unroll
  for (int d = 0; d < 4; ++d) { tv[d] = -FLT_MAX; tix[d] = 0; t20[d] = -FLT_MAX; }

  for (int jt = 0; jt < NT; ++jt) {
    const char* gtj = xhl + (size_t)(b * 32 + jt) * TILEB;
    cpyN<TILEB>(gtj, XjC, tid);
    if (tid < TJ) sqT[tid] = sqg[b * N + jt * TJ + tid];
    __syncthreads();   // Xj/sqT staged; prev selection (reads S) done

    f32x4 acc = {0, 0, 0, 0};
#pragma unroll
    for (int ks = 0; ks < C32 / 32; ++ks) {
      const int kc = ks * 32 + kb8;
      const bfrag ah = ldfragB<RB>(XiHp, 16 * ri + m15, kc);
      const bfrag al = ldfragB<RB>(XiLp, 16 * ri + m15, kc);
      const bfrag bh = ldfragB<RB>(XjHp, 16 * ci + m15, kc);
      const bfrag bl = ldfragB<RB>(XjLp, 16 * ci + m15, kc);
      acc = mfma_bf(ah, bh, acc);
      acc = mfma_bf(ah, bl, acc);
      acc = mfma_bf(al, bh, acc);
    }
#pragma unroll
    for (int r = 0; r < 4; ++r)
      S[16 * ri + (lane >> 4) * 4 + r][16 * ci + m15] = acc[r];
    const float sqv = sqT[lane];   // hoisted between barriers
    __syncthreads();   // S complete

    const int j0 = jt * TJ;
#pragma unroll
    for (int d = 0; d < 4; ++d) {
      const float sc = 2.f * S[4 * w + d][lane] - sqv;
      if (jt == 0) {
        float v = sc; int ixv = lane;    // j0 == 0
        bitonic64(v, ixv, lane);
        tv[d]  = (lane < TK) ? v : -FLT_MAX;
        tix[d] = (lane < TK) ? ixv : 0;
        t20[d] = readlane_f(tv[d], TK - 1);
      } else {
        unsigned long long mm = __ballot(sc > t20[d]);
        if (mm) {
          while (mm) {
            const int src = __ffsll(mm) - 1;
            mm &= mm - 1;
            const float cv = readlane_f(sc, src);
            const int   ci2 = j0 + src;
            const float pv_ = __shfl_up(tv[d], 1);
            const int   pi_ = __shfl_up(tix[d], 1);
            const unsigned long long g =
                __ballot(tv[d] > cv || (tv[d] == cv && tix[d] < ci2));
            const int p = __popcll(g);     // wave-uniform
            float nv = (lane == p) ? cv  : ((lane > p) ? pv_ : tv[d]);
            int   ni = (lane == p) ? ci2 : ((lane > p) ? pi_ : tix[d]);
            tv[d]  = (lane >= TK) ? -FLT_MAX : nv;
            tix[d] = (lane >= TK) ? 0 : ni;
          }
          t20[d] = readlane_f(tv[d], TK - 1);  // refresh once per tile
        }
      }
    }
  }
  if (lane < TK) {
#pragma unroll
    for (int d = 0; d < 4; ++d) {
      const int i = i0 + 4 * w + d;
      idx_out[((size_t)b * N + i) * TK + lane] = tix[d];
    }
  }
}

// ---------------- edgeconv: gather + fp16 MFMA + BN + LeakyReLU + max_k --------
// grid: b(16) x n-tile(128) = 2048 blocks; y contiguous [16][2048][64]
template<int C, int C32>
__global__ __launch_bounds__(256)
void conv_kernel(const float* __restrict__ xA, const float* __restrict__ xB,
                 const int* __restrict__ idxg,
                 const float* __restrict__ W, const float* __restrict__ gam,
                 const float* __restrict__ bet, const float* __restrict__ mea,
                 const float* __restrict__ var, float* __restrict__ y) {
  constexpr int N = 2048, TK = 20, O = 64;
  constexpr int RB = C32 * 2;
  constexpr int CH8 = C32 / 8;
  const int b    = blockIdx.x >> 7;        // 0..15
  const int n0   = (blockIdx.x & 127) * 16;
  const int tid  = threadIdx.x;
  const int lane = tid & 63;
  const int w    = tid >> 6;

  __shared__ float    ctrF[16][C];
  __shared__ _Float16 A1[320 * C32];
  __shared__ _Float16 CtrB[16 * C32];
  __shared__ _Float16 WdT[O * C32];
  __shared__ _Float16 WcT[O * C32];

  const float* xb = xbase<C>(xA, xB, b);

  for (int i = tid; i < 16 * C; i += 256)
    ctrF[i / C][i % C] = xb[(size_t)(n0 + i / C) * C + (i % C)];

  for (int i = tid; i < O * CH8; i += 256) {
    const int o = i / CH8, ch = (i % CH8) * 8;
    hfrag hd, hc;
#pragma unroll
    for (int e = 0; e < 8; ++e) {
      const int c = ch + e;
      hd[e] = (c < C) ? (_Float16)W[o * 2 * C + c]     : (_Float16)0.f;
      hc[e] = (c < C) ? (_Float16)W[o * 2 * C + C + c] : (_Float16)0.f;
    }
    const unsigned off = swz<RB>(o, ch * 2);
    *(hfrag*)((char*)WdT + off) = hd;
    *(hfrag*)((char*)WcT + off) = hc;
  }
  __syncthreads();

  for (int i = tid; i < 16 * CH8; i += 256) {
    const int row = i / CH8, ch = (i % CH8) * 8;
    hfrag hv;
#pragma unroll
    for (int e = 0; e < 8; ++e) {
      const int c = ch + e;
      hv[e] = (c < C) ? (_Float16)ctrF[row][c] : (_Float16)0.f;
    }
    *(hfrag*)((char*)CtrB + swz<RB>(row, ch * 2)) = hv;
  }

  for (int r = tid; r < 16 * TK; r += 256) {
    const int n = r & 15, k = r >> 4;
    int j = idxg[((size_t)b * N + n0 + n) * TK + k];
    j &= (N - 1);  // safety clamp
    const float* xj = xb + (size_t)j * C;
#pragma unroll
    for (int ch = 0; ch < C32; ch += 8) {
      float f[8];
#pragma unroll
      for (int q = 0; q < 8; q += 4) {
        const int c = ch + q;
        if (c + 3 < C) {
          *(f4v*)(f + q) = *(const f4v*)(xj + c);
        } else {
#pragma unroll
          for (int e = 0; e < 4; ++e) f[q + e] = (c + e < C) ? xj[c + e] : 0.f;
        }
      }
      hfrag hv;
#pragma unroll
      for (int e = 0; e < 8; ++e) {
        const int c = ch + e;
        const float d = (c < C) ? (f[e] - ctrF[n][c]) : 0.f;
        hv[e] = (_Float16)d;
      }
      *(hfrag*)((char*)A1 + swz<RB>(r, ch * 2)) = hv;
    }
  }
  __syncthreads();

  const int m15 = lane & 15;
  const int kb8 = (lane >> 4) * 8;
  hfrag bd[C32 / 32], bc[C32 / 32];
#pragma unroll
  for (int ks = 0; ks < C32 / 32; ++ks) {
    bd[ks] = ldfragH<RB>(WdT, 16 * w + m15, ks * 32 + kb8);
    bc[ks] = ldfragH<RB>(WcT, 16 * w + m15, ks * 32 + kb8);
  }
  f32x4 base = {0, 0, 0, 0};
#pragma unroll
  for (int ks = 0; ks < C32 / 32; ++ks)
    base = mfma_h(ldfragH<RB>(CtrB, m15, ks * 32 + kb8), bc[ks], base);

  f32x4 mx = {-FLT_MAX, -FLT_MAX, -FLT_MAX, -FLT_MAX};
#pragma unroll
  for (int k = 0; k < TK; ++k) {
    f32x4 a = {0, 0, 0, 0};
#pragma unroll
    for (int ks = 0; ks < C32 / 32; ++ks)
      a = mfma_h(ldfragH<RB>(A1, 16 * k + m15, ks * 32 + kb8), bd[ks], a);
#pragma unroll
    for (int r = 0; r < 4; ++r) mx[r] = fmaxf(mx[r], a[r] + base[r]);
  }

  const int o = 16 * w + m15;
  const float scv = gam[o] / sqrtf(var[o] + 1e-5f);
  const float shv = bet[o] - mea[o] * scv;
#pragma unroll
  for (int r = 0; r < 4; ++r) {
    const int n = (lane >> 4) * 4 + r;
    float v = scv * mx[r] + shv;
    v = (v >= 0.f) ? v : 0.2f * v;
    y[((size_t)b * N + n0 + n) * O + o] = v;
  }
}

// ---------------- attention pooling (16 batches, contiguous emb) -------------
__global__ __launch_bounds__(256)
void att_mean_kernel(const float* __restrict__ emb, float* __restrict__ msum) {
  constexpr int N = 2048, F = 64;
  const int b    = blockIdx.x >> 4;          // 0..15
  const int slab = blockIdx.x & 15;          // 128 rows per slab
  const int tid  = threadIdx.x;
  const int f = tid & 63, p = tid >> 6;
  __shared__ float part[4][F];
  float acc = 0.f;
  const float* e = emb + ((size_t)b * N + slab * 128) * F;
  for (int n = p; n < 128; n += 4) acc += e[(size_t)n * F + f];
  part[p][f] = acc;
  __syncthreads();
  if (tid < F)
    atomicAdd(&msum[b * F + tid],
              part[0][tid] + part[1][tid] + part[2][tid] + part[3][tid]);
}

__global__ __launch_bounds__(64)
void att_ctx_kernel(const float* __restrict__ msum, const float* __restrict__ Watt,
                    float* __restrict__ ctx) {
  constexpr int N = 2048, F = 64;
  const int b = blockIdx.x, tid = threadIdx.x;
  __shared__ float m[F];
  m[tid] = msum[b * F + tid] * (1.f / N);
  __syncthreads();
  float a = 0.f;
  for (int ff = 0; ff < F; ++ff) a += m[ff] * Watt[ff * F + tid];
  ctx[b * F + tid] = tanhf(a);
}

__global__ __launch_bounds__(256)
void att2_kernel(const float* __restrict__ emb, const float* __restrict__ ctx,
                 float* __restrict__ eout) {
  constexpr int N = 2048, F = 64;
  const int b   = blockIdx.x >> 3;           // 0..15
  const int c0  = (blockIdx.x & 7) * 256;
  const int tid = threadIdx.x, lane = tid & 63, w = tid >> 6;
  const float cv = ctx[b * F + lane];
  float acc = 0.f;
  const float* e = emb + (size_t)b * N * F;
  for (int n = c0 + w * 64; n < c0 + (w + 1) * 64; ++n) {
    const float v = e[(size_t)n * F + lane];
    float d = v * cv;
#pragma unroll
    for (int off = 1; off < 64; off <<= 1) d += __shfl_xor(d, off);
    const float s = 1.f / (1.f + expf(-d));
    acc += v * s;
  }
  atomicAdd(&eout[b * F + lane], acc);
}

// ---------------- tensor network ----------------
__global__ __launch_bounds__(256)
void tn_kernel(const float* __restrict__ ep,
               const float* __restrict__ Wt, const float* __restrict__ Wb,
               const float* __restrict__ bias, float* __restrict__ out) {
  constexpr int F = 64, T = 16;
  const int b = blockIdx.x, tid = threadIdx.x;
  __shared__ float s1[F], s2[F];
  __shared__ float part[T][17];
  if (tid < F) { s1[tid] = ep[b * F + tid]; s2[tid] = ep[(b + 8) * F + tid]; }
  __syncthreads();
  const int t = tid >> 4, sub = tid & 15;
  float a = 0.f;
  for (int f = sub * 4; f < sub * 4 + 4; ++f) {
    float inner = 0.f;
    for (int g = 0; g < F; ++g) inner += Wt[((f * F) + g) * T + t] * s2[g];
    a += s1[f] * inner;
  }
  part[t][sub] = a;
  __syncthreads();
  if (tid < T) {
    float v = 0.f;
    for (int q = 0; q < 16; ++q) v += part[tid][q];
    for (int f = 0; f < F; ++f)
      v += Wb[tid * 2 * F + f] * s1[f] + Wb[tid * 2 * F + F + f] * s2[f];
    v += bias[tid];
    out[b * T + tid] = fmaxf(v, 0.f);
  }
}

extern "C" void kernel_launch(void* const* d_in, const int* in_sizes, int n_in,
                              void* d_out, int out_size, void* d_ws, size_t ws_size,
                              hipStream_t stream) {
  const float* x1  = (const float*)d_in[0];
  const float* x2  = (const float*)d_in[1];
  const float* W1  = (const float*)d_in[2];
  const float* g1  = (const float*)d_in[3];
  const float* b1  = (const float*)d_in[4];
  const float* m1  = (const float*)d_in[5];
  const float* v1  = (const float*)d_in[6];
  const float* W2  = (const float*)d_in[7];
  const float* g2  = (const float*)d_in[8];
  const float* b2  = (const float*)d_in[9];
  const float* m2  = (const float*)d_in[10];
  const float* v2  = (const float*)d_in[11];
  const float* W3  = (const float*)d_in[12];
  const float* g3  = (const float*)d_in[13];
  const float* b3  = (const float*)d_in[14];
  const float* m3  = (const float*)d_in[15];
  const float* v3  = (const float*)d_in[16];
  const float* Wat = (const float*)d_in[17];
  const float* Wt  = (const float*)d_in[18];
  const float* Wb  = (const float*)d_in[19];
  const float* bs  = (const float*)d_in[20];
  float* out = (float*)d_out;

  constexpr size_t NF = (size_t)16 * 2048 * 64;   // 16 batches (both graphs)
  constexpr size_t XHLB = (size_t)16 * 32 * 16384;  // max tile-image bytes (C32=64)
  float* bufA = (float*)d_ws;
  float* bufB = bufA + NF;
  float* sqb  = bufB + NF;                        // 16*2048
  int*   idxb = (int*)(sqb + 16 * 2048);          // 16*2048*20
  char*  xhl  = (char*)(idxb + (size_t)16 * 2048 * 20);   // 8 MB
  float* msum = (float*)(xhl + XHLB);             // 16*64
  float* epool= msum + 16 * 64;                   // 16*64
  float* ctx  = epool + 16 * 64;                  // 16*64

  const float* bA8 = bufA + (size_t)8 * 2048 * 64;
  const float* bB8 = bufB + (size_t)8 * 2048 * 64;

  // layer 1: x(pair) -> bufA
  sq_kernel<12><<<128, 256, 0, stream>>>(x1, x2, sqb);
  cvt_kernel<12, 32><<<512, 256, 0, stream>>>(x1, x2, xhl);
  knn_kernel<32><<<1024, 512, 0, stream>>>(xhl, sqb, idxb);
  conv_kernel<12, 32><<<2048, 256, 0, stream>>>(x1, x2, idxb, W1, g1, b1, m1, v1, bufA);

  // layer 2: bufA -> bufB
  sq_kernel<64><<<128, 256, 0, stream>>>(bufA, bA8, sqb);
  cvt_kernel<64, 64><<<1024, 256, 0, stream>>>(bufA, bA8, xhl);
  knn_kernel<64><<<1024, 512, 0, stream>>>(xhl, sqb, idxb);
  conv_kernel<64, 64><<<2048, 256, 0, stream>>>(bufA, bA8, idxb, W2, g2, b2, m2, v2, bufB);

  // layer 3: bufB -> bufA (= final emb, 16 batches)
  sq_kernel<64><<<128, 256, 0, stream>>>(bufB, bB8, sqb);
  cvt_kernel<64, 64><<<1024, 256, 0, stream>>>(bufB, bB8, xhl);
  knn_kernel<64><<<1024, 512, 0, stream>>>(xhl, sqb, idxb);
  conv_kernel<64, 64><<<2048, 256, 0, stream>>>(bufB, bB8, idxb, W3, g3, b3, m3, v3, bufA);

  hipMemsetAsync(msum, 0, 2 * 16 * 64 * sizeof(float), stream);  // msum+epool
  att_mean_kernel<<<256, 256, 0, stream>>>(bufA, msum);
  att_ctx_kernel<<<16, 64, 0, stream>>>(msum, Wat, ctx);
  att2_kernel<<<128, 256, 0, stream>>>(bufA, ctx, epool);
  tn_kernel<<<8, 256, 0, stream>>>(epool, Wt, Wb, bs, out);
}